// Round 5
// baseline (323.000 us; speedup 1.0000x reference)
//
#include <hip/hip_runtime.h>

constexpr int NN = 100000;
constexpr int NE = 640000;
constexpr int D  = 128;
constexpr int NB = (NN + 255) / 256;  // 391

typedef __attribute__((ext_vector_type(8))) short bf16x8;
typedef __attribute__((ext_vector_type(4))) float f32x4;

__device__ __forceinline__ short f2bf(float f) {
    union { float f; unsigned u; } v; v.f = f;
    unsigned r = v.u + 0x7FFF + ((v.u >> 16) & 1);
    return (short)(r >> 16);
}
__device__ __forceinline__ float bf2f(short h) {
    union { unsigned u; float f; } v;
    v.u = ((unsigned)(unsigned short)h) << 16;
    return v.f;
}

// ---------------------------------------------------------------------------
// Counting sort of edges by dst: histogram -> scan -> position array
// ---------------------------------------------------------------------------
__global__ __launch_bounds__(256) void k_zero(int* __restrict__ cnt) {
    int i = blockIdx.x * 256 + threadIdx.x;
    if (i < NN) cnt[i] = 0;
}

__global__ __launch_bounds__(256) void k_hist(const int* __restrict__ dst,
                                              int* __restrict__ cnt) {
    int e = blockIdx.x * 256 + threadIdx.x;
    if (e < NE) atomicAdd(&cnt[dst[e]], 1);
}

__global__ __launch_bounds__(256) void k_bsum(const int* __restrict__ cnt,
                                              int* __restrict__ bsum) {
    int i = blockIdx.x * 256 + threadIdx.x;
    int v = (i < NN) ? cnt[i] : 0;
#pragma unroll
    for (int s = 32; s; s >>= 1) v += __shfl_down(v, s, 64);
    __shared__ int w[4];
    if ((threadIdx.x & 63) == 0) w[threadIdx.x >> 6] = v;
    __syncthreads();
    if (threadIdx.x == 0) bsum[blockIdx.x] = w[0] + w[1] + w[2] + w[3];
}

__global__ __launch_bounds__(512) void k_scan_bsum(const int* __restrict__ bsum,
                                                   int* __restrict__ bboff) {
    int t = threadIdx.x, lane = t & 63;
    int v = (t < NB) ? bsum[t] : 0;
    int incl = v;
#pragma unroll
    for (int s = 1; s < 64; s <<= 1) {
        int u = __shfl_up(incl, s, 64);
        if (lane >= s) incl += u;
    }
    __shared__ int wt[8], wp[8];
    if (lane == 63) wt[t >> 6] = incl;
    __syncthreads();
    if (t == 0) { int run = 0; for (int i = 0; i < 8; ++i) { wp[i] = run; run += wt[i]; } }
    __syncthreads();
    if (t < NB) bboff[t] = incl - v + wp[t >> 6];
}

__global__ __launch_bounds__(256) void k_scan_final(const int* __restrict__ cnt,
                                                    const int* __restrict__ bboff,
                                                    int* __restrict__ off,
                                                    int* __restrict__ cur) {
    int b = blockIdx.x, t = threadIdx.x, lane = t & 63;
    int i = b * 256 + t;
    int v = (i < NN) ? cnt[i] : 0;
    int incl = v;
#pragma unroll
    for (int s = 1; s < 64; s <<= 1) {
        int u = __shfl_up(incl, s, 64);
        if (lane >= s) incl += u;
    }
    __shared__ int wt[4], wp[4];
    if (lane == 63) wt[t >> 6] = incl;
    __syncthreads();
    if (t == 0) { int run = 0; for (int q = 0; q < 4; ++q) { wp[q] = run; run += wt[q]; } }
    __syncthreads();
    int excl = incl - v + wp[t >> 6] + bboff[b];
    if (i < NN) { off[i] = excl; cur[i] = excl; }
    if (i == 0) off[NN] = NE;
}

__global__ __launch_bounds__(256) void k_pos(const int* __restrict__ dst,
                                             int* __restrict__ cur,
                                             int* __restrict__ pos) {
    int e = blockIdx.x * 256 + threadIdx.x;
    if (e < NE) pos[e] = atomicAdd(&cur[dst[e]], 1);
}

// ---------------------------------------------------------------------------
// W pre-split: W[k][n] f32 -> Wt_hi[n][k], Wt_lo[n][k] bf16
// ---------------------------------------------------------------------------
__global__ __launch_bounds__(256) void k_wsplit(const float* __restrict__ W,
                                                short* __restrict__ Whi,
                                                short* __restrict__ Wlo) {
    for (int idx = blockIdx.x * 256 + threadIdx.x; idx < D * D; idx += gridDim.x * 256) {
        int n = idx >> 7, k = idx & 127;
        float w = W[k * D + n];
        short hi = f2bf(w);
        Whi[idx] = hi;
        Wlo[idx] = f2bf(w - bf2f(hi));
    }
}

// ---------------------------------------------------------------------------
// Phase 1 (edge order, streaming): mbuf[pos[e]] = bf16(relu(x[src[e]] + ea[e]))
// 16 threads per edge, 8 floats each: ea read fully sequential, x row gather
// (L3-resident), 256 B full-line scatter write (no RMW amplification).
// ---------------------------------------------------------------------------
__global__ __launch_bounds__(256) void k_msg(const float* __restrict__ x,
                                             const int* __restrict__ src,
                                             const float* __restrict__ ea,
                                             const int* __restrict__ pos,
                                             unsigned short* __restrict__ mbuf) {
    unsigned gid = blockIdx.x * 256 + threadIdx.x;
    unsigned e = gid >> 4;          // grid sized exactly: e < NE always
    unsigned c = gid & 15;          // 8-float chunk
    const int s = src[e];
    const int p = pos[e];
    const float* eap = ea + (size_t)e * D + c * 8;
    const float* xp  = x  + (size_t)s * D + c * 8;
    float4 a0 = reinterpret_cast<const float4*>(xp)[0];
    float4 a1 = reinterpret_cast<const float4*>(xp)[1];
    float4 b0 = reinterpret_cast<const float4*>(eap)[0];
    float4 b1 = reinterpret_cast<const float4*>(eap)[1];
    float m[8] = {a0.x + b0.x, a0.y + b0.y, a0.z + b0.z, a0.w + b0.w,
                  a1.x + b1.x, a1.y + b1.y, a1.z + b1.z, a1.w + b1.w};
    bf16x8 o;
#pragma unroll
    for (int i = 0; i < 8; ++i) o[i] = f2bf(fmaxf(m[i], 0.0f));
    *reinterpret_cast<bf16x8*>(mbuf + (size_t)p * D + c * 8) = o;
}

// ---------------------------------------------------------------------------
// Phase 2 (node order, streaming): h[n] = (1+eps)*x[n] + sum of mbuf segment.
// One wave per node; lane owns 2 columns (4 B per message row). Segments are
// contiguous and sorted -> sequential mbuf read. Unroll-4 batched loads.
// ---------------------------------------------------------------------------
__global__ __launch_bounds__(256) void k_agg2(const float* __restrict__ x,
                                              const unsigned short* __restrict__ mbuf,
                                              const int* __restrict__ off,
                                              const float* __restrict__ eps,
                                              float* __restrict__ h) {
    int wave = threadIdx.x >> 6;
    int lane = threadIdx.x & 63;
    int n = blockIdx.x * 4 + wave;
    if (n >= NN) return;
    int j0 = off[n], j1 = off[n + 1];
    const int lo2 = lane * 2;
    float accx = 0.0f, accy = 0.0f;

    for (int j = j0; j < j1; j += 4) {
        ushort2 mv[4];
#pragma unroll
        for (int q = 0; q < 4; ++q) {
            int jj = j + q; jj = (jj < j1) ? jj : (j1 - 1);
            mv[q] = *reinterpret_cast<const ushort2*>(mbuf + (size_t)jj * D + lo2);
        }
#pragma unroll
        for (int q = 0; q < 4; ++q) {
            bool ok = (j + q) < j1;
            accx += ok ? bf2f((short)mv[q].x) : 0.0f;
            accy += ok ? bf2f((short)mv[q].y) : 0.0f;
        }
    }
    float sc = 1.0f + eps[0];
    float2 xx = *reinterpret_cast<const float2*>(x + (size_t)n * D + lo2);
    float2 o;
    o.x = fmaf(sc, xx.x, accx);
    o.y = fmaf(sc, xx.y, accy);
    *reinterpret_cast<float2*>(h + (size_t)n * D + lo2) = o;
}

// ---------------------------------------------------------------------------
// Fused 2-layer MLP via bf16x3 MFMA (unchanged from round 4).
// ---------------------------------------------------------------------------
__global__ __launch_bounds__(256) void k_mlp2(const float* __restrict__ A,
                                              const short* __restrict__ W1h,
                                              const short* __restrict__ W1l,
                                              const short* __restrict__ W2h,
                                              const short* __restrict__ W2l,
                                              const float* __restrict__ b1,
                                              const float* __restrict__ b2,
                                              float* __restrict__ out) {
    __shared__ float G[4][32][D];  // 64 KB, per-wave 16 KB tiles

    const int wave = threadIdx.x >> 6;
    const int lane = threadIdx.x & 63;
    const int r = lane & 15;
    const int g = lane >> 4;

    const long rb = (long)blockIdx.x * 128 + wave * 32;

    f32x4 acc1[2][8];
#pragma unroll
    for (int mt = 0; mt < 2; ++mt)
#pragma unroll
        for (int nt = 0; nt < 8; ++nt) {
            acc1[mt][nt].x = 0.f; acc1[mt][nt].y = 0.f;
            acc1[mt][nt].z = 0.f; acc1[mt][nt].w = 0.f;
        }

#pragma unroll
    for (int kc = 0; kc < 4; ++kc) {
        const int k0 = kc * 32;
        bf16x8 ahi[2], alo[2];
#pragma unroll
        for (int mt = 0; mt < 2; ++mt) {
            long row = rb + mt * 16 + r;
            row = (row < NN) ? row : (NN - 1);
            const float* ap = A + row * D + k0 + g * 8;
            float4 v0 = reinterpret_cast<const float4*>(ap)[0];
            float4 v1 = reinterpret_cast<const float4*>(ap)[1];
            float vals[8] = {v0.x, v0.y, v0.z, v0.w, v1.x, v1.y, v1.z, v1.w};
#pragma unroll
            for (int i = 0; i < 8; ++i) {
                short hb = f2bf(vals[i]);
                ahi[mt][i] = hb;
                alo[mt][i] = f2bf(vals[i] - bf2f(hb));
            }
        }
#pragma unroll
        for (int nt = 0; nt < 8; ++nt) {
            const int wb = (nt * 16 + r) * D + k0 + g * 8;
            bf16x8 whi = *reinterpret_cast<const bf16x8*>(&W1h[wb]);
            bf16x8 wlo = *reinterpret_cast<const bf16x8*>(&W1l[wb]);
#pragma unroll
            for (int mt = 0; mt < 2; ++mt) {
                acc1[mt][nt] = __builtin_amdgcn_mfma_f32_16x16x32_bf16(ahi[mt], whi, acc1[mt][nt], 0, 0, 0);
                acc1[mt][nt] = __builtin_amdgcn_mfma_f32_16x16x32_bf16(ahi[mt], wlo, acc1[mt][nt], 0, 0, 0);
                acc1[mt][nt] = __builtin_amdgcn_mfma_f32_16x16x32_bf16(alo[mt], whi, acc1[mt][nt], 0, 0, 0);
            }
        }
    }

#pragma unroll
    for (int nt = 0; nt < 8; ++nt) {
        const int col = nt * 16 + r;
        const float bb = b1[col];
#pragma unroll
        for (int mt = 0; mt < 2; ++mt) {
#pragma unroll
            for (int q = 0; q < 4; ++q) {
                float v = fmaxf(acc1[mt][nt][q] + bb, 0.0f);
                G[wave][mt * 16 + g * 4 + q][col] = v;
            }
        }
    }
    __syncthreads();

    f32x4 acc2[2][8];
#pragma unroll
    for (int mt = 0; mt < 2; ++mt)
#pragma unroll
        for (int nt = 0; nt < 8; ++nt) {
            acc2[mt][nt].x = 0.f; acc2[mt][nt].y = 0.f;
            acc2[mt][nt].z = 0.f; acc2[mt][nt].w = 0.f;
        }

#pragma unroll
    for (int kc = 0; kc < 4; ++kc) {
        const int k0 = kc * 32;
        bf16x8 ahi[2], alo[2];
#pragma unroll
        for (int mt = 0; mt < 2; ++mt) {
            const float* gp = &G[wave][mt * 16 + r][k0 + g * 8];
            float4 v0 = reinterpret_cast<const float4*>(gp)[0];
            float4 v1 = reinterpret_cast<const float4*>(gp)[1];
            float vals[8] = {v0.x, v0.y, v0.z, v0.w, v1.x, v1.y, v1.z, v1.w};
#pragma unroll
            for (int i = 0; i < 8; ++i) {
                short hb = f2bf(vals[i]);
                ahi[mt][i] = hb;
                alo[mt][i] = f2bf(vals[i] - bf2f(hb));
            }
        }
#pragma unroll
        for (int nt = 0; nt < 8; ++nt) {
            const int wb = (nt * 16 + r) * D + k0 + g * 8;
            bf16x8 whi = *reinterpret_cast<const bf16x8*>(&W2h[wb]);
            bf16x8 wlo = *reinterpret_cast<const bf16x8*>(&W2l[wb]);
#pragma unroll
            for (int mt = 0; mt < 2; ++mt) {
                acc2[mt][nt] = __builtin_amdgcn_mfma_f32_16x16x32_bf16(ahi[mt], whi, acc2[mt][nt], 0, 0, 0);
                acc2[mt][nt] = __builtin_amdgcn_mfma_f32_16x16x32_bf16(ahi[mt], wlo, acc2[mt][nt], 0, 0, 0);
                acc2[mt][nt] = __builtin_amdgcn_mfma_f32_16x16x32_bf16(alo[mt], whi, acc2[mt][nt], 0, 0, 0);
            }
        }
    }

#pragma unroll
    for (int nt = 0; nt < 8; ++nt) {
        const int col = nt * 16 + r;
        const float bb = b2[col];
#pragma unroll
        for (int mt = 0; mt < 2; ++mt) {
#pragma unroll
            for (int q = 0; q < 4; ++q) {
                long row = rb + mt * 16 + g * 4 + q;
                if (row < NN) out[row * D + col] = acc2[mt][nt][q] + bb;
            }
        }
    }
}

// ---------------------------------------------------------------------------
extern "C" void kernel_launch(void* const* d_in, const int* in_sizes, int n_in,
                              void* d_out, int out_size, void* d_ws, size_t ws_size,
                              hipStream_t stream) {
    const float* x   = (const float*)d_in[0];
    const int*   ei  = (const int*)d_in[1];   // int32 [2, NE]
    const float* ea  = (const float*)d_in[2];
    const float* eps = (const float*)d_in[3];
    const float* W1  = (const float*)d_in[4];
    const float* b1  = (const float*)d_in[5];
    const float* W2  = (const float*)d_in[6];
    const float* b2  = (const float*)d_in[7];
    float* out = (float*)d_out;

    const int* src = ei;
    const int* dst = ei + NE;

    // ws layout
    int* base  = (int*)d_ws;
    int* cnt   = base;                 // NN
    int* off   = cnt + NN;             // NN+1
    int* cur   = off + NN + 1;         // NN
    int* bsum  = cur + NN;             // NB
    int* bboff = bsum + NB;            // NB
    int* pos   = bboff + NB;           // NE
    size_t mb_off = ((size_t)(3 * NN + 1 + 2 * NB + NE) + 63) & ~(size_t)63;  // 256B align
    unsigned short* mbuf = (unsigned short*)(base + mb_off);  // NE*D bf16 = 164 MB
    short* wsp = (short*)(mbuf + (size_t)NE * D);
    short* W1h = wsp;                  // D*D each
    short* W1l = W1h + D * D;
    short* W2h = W1l + D * D;
    short* W2l = W2h + D * D;

    k_wsplit    <<<32,               256, 0, stream>>>(W1, W1h, W1l);
    k_wsplit    <<<32,               256, 0, stream>>>(W2, W2h, W2l);
    k_zero      <<<NB,               256, 0, stream>>>(cnt);
    k_hist      <<<(NE + 255) / 256, 256, 0, stream>>>(dst, cnt);
    k_bsum      <<<NB,               256, 0, stream>>>(cnt, bsum);
    k_scan_bsum <<<1,                512, 0, stream>>>(bsum, bboff);
    k_scan_final<<<NB,               256, 0, stream>>>(cnt, bboff, off, cur);
    k_pos       <<<(NE + 255) / 256, 256, 0, stream>>>(dst, cur, pos);

    // edge-order streaming: mbuf[pos[e]] = bf16(relu(x[src]+ea))
    k_msg <<<NE * 16 / 256, 256, 0, stream>>>(x, src, ea, pos, mbuf);
    // node-order streaming: h = (1+eps)x + segment_sum(mbuf)  -> d_out
    k_agg2<<<(NN + 3) / 4, 256, 0, stream>>>(x, mbuf, off, eps, out);
    // out = relu(out @ W1 + b1) @ W2 + b2
    k_mlp2<<<(NN + 127) / 128, 256, 0, stream>>>(out, W1h, W1l, W2h, W2l, b1, b2, out);
}